// Round 4
// baseline (923.298 us; speedup 1.0000x reference)
//
#include <hip/hip_runtime.h>
#include <stdint.h>

#define E_ 8
#define S_ 8192
#define H_ 2048
#define F_ 8192
#define C_ 1024
#define OUTN (S_*H_)

typedef __bf16 bf16x8 __attribute__((ext_vector_type(8)));
typedef float  f32x4  __attribute__((ext_vector_type(4)));
typedef unsigned short us8 __attribute__((ext_vector_type(8)));

__device__ __forceinline__ unsigned short f2bf(float f) {
    union { float f; unsigned u; } v; v.f = f;
    unsigned r = (v.u + 0x7FFFu + ((v.u >> 16) & 1u)) >> 16;
    return (unsigned short)r;
}

__device__ __forceinline__ void gload16(const void* g, void* l) {
    auto gp = (const __attribute__((address_space(1))) void*)(unsigned long long)(uintptr_t)g;
    auto lp = (__attribute__((address_space(3))) void*)(unsigned int)(uintptr_t)l;
    __builtin_amdgcn_global_load_lds(gp, lp, 16, 0, 0);
}

#define SB() __builtin_amdgcn_sched_barrier(0)
#define BAR() do { SB(); __builtin_amdgcn_s_barrier(); SB(); } while(0)

// ---------------- zero d_out ----------------
__global__ void zero_kernel(float* __restrict__ o, int n) {
    int i = blockIdx.x * blockDim.x + threadIdx.x;
    int st = gridDim.x * blockDim.x;
    for (; i < n; i += st) o[i] = 0.f;
}

// ---------------- transpose + fp32->bf16: dst[e][n][k] = src[e][k][n] ----------------
__global__ __launch_bounds__(256)
void transpose_cvt(const float* __restrict__ src, unsigned short* __restrict__ dst,
                   int R, int Cc)
{
    __shared__ float t[64][65];
    int tilesR = R >> 6, tilesC = Cc >> 6;
    int per_e = tilesR * tilesC;
    int bid = blockIdx.x;
    int e  = bid / per_e;
    int rm = bid - e * per_e;
    int tc = rm / tilesR;
    int tr = rm - tc * tilesR;

    const float* s = src + (size_t)e * R * Cc + (size_t)(tr * 64) * Cc + tc * 64;
    int tid = threadIdx.x;
    int rr = tid >> 4;
    int cc = (tid & 15) << 2;
#pragma unroll
    for (int i = 0; i < 4; i++) {
        float4 v = *(const float4*)(s + (size_t)(rr + i * 16) * Cc + cc);
        t[rr + i * 16][cc + 0] = v.x;
        t[rr + i * 16][cc + 1] = v.y;
        t[rr + i * 16][cc + 2] = v.z;
        t[rr + i * 16][cc + 3] = v.w;
    }
    __syncthreads();
    int nl = tid >> 2;
    int kq = (tid & 3) << 4;
    us8 o0, o1;
#pragma unroll
    for (int i = 0; i < 8; i++) o0[i] = f2bf(t[kq + i][nl]);
#pragma unroll
    for (int i = 0; i < 8; i++) o1[i] = f2bf(t[kq + 8 + i][nl]);
    unsigned short* d = dst + (size_t)e * R * Cc + (size_t)(tc * 64 + nl) * R + tr * 64 + kq;
    *reinterpret_cast<us8*>(d)     = o0;
    *reinterpret_cast<us8*>(d + 8) = o1;
}

// ---------------- gating ----------------
__global__ __launch_bounds__(256)
void gating_kernel(const float* __restrict__ x, const float* __restrict__ wg,
                   int* __restrict__ expert_id, float* __restrict__ gate_tok,
                   float* __restrict__ gates_all)
{
    int lane = threadIdx.x & 63;
    int wid  = threadIdx.x >> 6;
    int s = blockIdx.x * 4 + wid;
    const float* xs = x + (size_t)s * H_;
    float p[8];
#pragma unroll
    for (int j = 0; j < 8; j++) p[j] = 0.f;
    for (int h = lane; h < H_; h += 64) {
        float xv = xs[h];
        const float4* w4 = (const float4*)(wg + (size_t)h * 8);
        float4 a = w4[0], b = w4[1];
        p[0] += xv * a.x; p[1] += xv * a.y; p[2] += xv * a.z; p[3] += xv * a.w;
        p[4] += xv * b.x; p[5] += xv * b.y; p[6] += xv * b.z; p[7] += xv * b.w;
    }
#pragma unroll
    for (int off = 32; off; off >>= 1) {
#pragma unroll
        for (int j = 0; j < 8; j++) p[j] += __shfl_xor(p[j], off);
    }
    if (lane == 0) {
        float mx = p[0];
#pragma unroll
        for (int j = 1; j < 8; j++) mx = fmaxf(mx, p[j]);
        float ex[8], sum = 0.f;
#pragma unroll
        for (int j = 0; j < 8; j++) { ex[j] = expf(p[j] - mx); sum += ex[j]; }
        float inv = 1.f / sum;
        int am = 0; float best = p[0];
#pragma unroll
        for (int j = 1; j < 8; j++) if (p[j] > best) { best = p[j]; am = j; }
        expert_id[s] = am;
        gate_tok[s]  = expf(best - mx) * inv;
        float* ga = gates_all + (size_t)s * 8;
#pragma unroll
        for (int j = 0; j < 8; j++) ga[j] = ex[j] * inv;
    }
}

// ---------------- single-block capacity scan + l_aux + exp_counts ----------------
__global__ __launch_bounds__(1024)
void scan_kernel(const int* __restrict__ expert_id,
                 const float* __restrict__ gate_tok,
                 const float* __restrict__ gates_all,
                 int* __restrict__ token_slot,
                 float* __restrict__ gate_slot,
                 float* __restrict__ out_tail)
{
    __shared__ unsigned long long wt0[16], wt1[16];
    __shared__ unsigned long long tot0s, tot1s;
    __shared__ float red[1024 * 8];

    int tid = threadIdx.x;
    for (int i = tid; i < E_ * C_; i += 1024) token_slot[i] = -1;

    int ids[8];
#pragma unroll
    for (int j = 0; j < 8; j++) ids[j] = expert_id[tid * 8 + j];

    unsigned long long c0 = 0, c1 = 0;
#pragma unroll
    for (int j = 0; j < 8; j++) {
        int e = ids[j];
        unsigned long long inc = 1ull << ((e & 3) * 16);
        if (e < 4) c0 += inc; else c1 += inc;
    }
    unsigned long long s0 = c0, s1 = c1;
    int lane = tid & 63, w = tid >> 6;
#pragma unroll
    for (int off = 1; off < 64; off <<= 1) {
        unsigned long long t0 = __shfl_up(s0, off);
        unsigned long long t1 = __shfl_up(s1, off);
        if (lane >= off) { s0 += t0; s1 += t1; }
    }
    if (lane == 63) { wt0[w] = s0; wt1[w] = s1; }
    __syncthreads();
    unsigned long long off0 = 0, off1 = 0;
    for (int i = 0; i < w; i++) { off0 += wt0[i]; off1 += wt1[i]; }
    unsigned long long p0 = off0 + s0 - c0;
    unsigned long long p1 = off1 + s1 - c1;

#pragma unroll
    for (int j = 0; j < 8; j++) {
        int stok = tid * 8 + j;
        int e = ids[j];
        int sh = (e & 3) * 16;
        int slot = (int)(((e < 4 ? p0 : p1) >> sh) & 0xFFFFull);
        if (slot < C_) {
            token_slot[e * C_ + slot] = stok;
            gate_slot[e * C_ + slot]  = gate_tok[stok];
        }
        if (e < 4) p0 += 1ull << sh; else p1 += 1ull << sh;
    }
    if (tid == 1023) { tot0s = off0 + s0; tot1s = off1 + s1; }

    float me[8];
#pragma unroll
    for (int e2 = 0; e2 < 8; e2++) me[e2] = 0.f;
#pragma unroll
    for (int j = 0; j < 8; j++) {
        const float* ga = gates_all + (size_t)(tid * 8 + j) * 8;
#pragma unroll
        for (int e2 = 0; e2 < 8; e2++) me[e2] += ga[e2];
    }
#pragma unroll
    for (int e2 = 0; e2 < 8; e2++) red[tid * 8 + e2] = me[e2];
    __syncthreads();
    for (int st = 512; st > 0; st >>= 1) {
        if (tid < st) {
#pragma unroll
            for (int e2 = 0; e2 < 8; e2++) red[tid * 8 + e2] += red[(tid + st) * 8 + e2];
        }
        __syncthreads();
    }
    if (tid == 0) {
        float laux = 0.f;
#pragma unroll
        for (int e2 = 0; e2 < 8; e2++) {
            unsigned long long tv = (e2 < 4) ? tot0s : tot1s;
            float cnt = (float)((tv >> ((e2 & 3) * 16)) & 0xFFFFull);
            laux += red[e2] * cnt;
            out_tail[1 + e2] = cnt;
        }
        out_tail[0] = laux * (8.f / (8192.f * 8192.f));
    }
}

// ---------------- gather dispatched rows (fp32 -> bf16) ----------------
__global__ __launch_bounds__(256)
void gather_kernel(const float* __restrict__ x, const int* __restrict__ token_slot,
                   unsigned short* __restrict__ disp)
{
    int slot = blockIdx.x;
    int tok = token_slot[slot];
    int t = threadIdx.x;
    us8* d = reinterpret_cast<us8*>(disp + (size_t)slot * H_ + t * 8);
    if (tok < 0) {
        us8 z;
#pragma unroll
        for (int i = 0; i < 8; i++) z[i] = 0;
        *d = z;
        return;
    }
    const float4* s4 = (const float4*)(x + (size_t)tok * H_ + t * 8);
    float4 a = s4[0], b = s4[1];
    us8 o;
    o[0] = f2bf(a.x); o[1] = f2bf(a.y); o[2] = f2bf(a.z); o[3] = f2bf(a.w);
    o[4] = f2bf(b.x); o[5] = f2bf(b.y); o[6] = f2bf(b.z); o[7] = f2bf(b.w);
    *d = o;
}

// ============ 256x256 bf16 GEMM, 2 super-phases/K-tile (T2+T3+T4+T5) ============
// A [E*1024][K] bf16, B [E][N][K] bf16 (pre-transposed). BM=BN=256, BK=64,
// 512 thr = 8 waves (2M x 4N). LDS 128 KiB dbuf, typed uint4 (force ds_read_b128).
// SP0: read A-lo(8)+B-all(8); stage A-Q1/Q3(t+1); BAR; 32 MFMA; vmcnt(8); BAR.
// SP1: read A-hi(8);          stage B(t+2)+A-Q0/Q2(t+2); BAR; 32 MFMA; vmcnt(8); BAR.
// Quarter regions (8KB): A-Qj last read: Q0,Q2 in SP0; Q1,Q3 in SP1. B: SP0.
// Tail: end-SP1(NTI-2)=vmcnt(2); end-SP0(NTI-1)=vmcnt(0).
template<int EPI, int K, int N>
__global__ __launch_bounds__(512, 2)
void gemm2sp(const unsigned short* __restrict__ A,
             const unsigned short* __restrict__ B,
             const float* __restrict__ bias,
             unsigned short* __restrict__ hout,
             float* __restrict__ fout,
             const int* __restrict__ token_slot,
             const float* __restrict__ gate_slot,
             int Mt, int Nt)
{
    __shared__ uint4 shm[8192];                 // 131072 B
    constexpr int KB   = K * 2;                 // global row pitch (bytes)
    constexpr int QG   = 64 * KB;               // 64-row quarter pitch (bytes)
    constexpr int NTI  = K / 64;                // K-tiles (>=3)

    int nwg = gridDim.x;
    int bid = blockIdx.x;
    int cpx = nwg >> 3;
    int wg  = (bid & 7) * cpx + (bid >> 3);     // XCD-contiguous
    int per_e = Mt * Nt;
    int e  = wg / per_e;
    int r  = wg - e * per_e;
    int nt = r / Mt;
    int mt = r - nt * Mt;

    int tid  = threadIdx.x;
    int lane = tid & 63;
    int wid  = tid >> 6;
    int wr = wid >> 2, wc = wid & 3;

    const char* Ag = (const char*)(A + ((size_t)e * 1024 + (size_t)mt * 256) * (size_t)K);
    const char* Bg = (const char*)(B + ((size_t)e * N    + (size_t)nt * 256) * (size_t)K);

    // staging source offset (inverse st_16x32 swizzle on global src), 64-row quarter
    int r16s   = (tid >> 2) & 15;
    int scs    = ((tid & 3) * 16) ^ ((r16s & 8) << 2);
    int colblk = (tid >> 6) & 1;
    int rb0    = tid >> 7;
    int off0 = (rb0 * 16 + r16s) * KB + colblk * 64 + scs;
    int widb = wid * 1024;

    // swizzled LDS read offset (bytes within 8KB quarter)
    int lread = (lane & 15) * 64 + (((lane >> 4) * 16) ^ ((lane & 8) << 2));

    // stage one 8KB quarter: dstbyte = LDS byte base, src = global quarter base
    auto SQ = [&](int dstbyte, const char* src) {
        gload16(src + off0, (char*)shm + dstbyte + widb);
    };
    // LDS map: Abuf(b) = b*32768 + j*8192 (j=0..3); Bbuf(b) = 65536 + b*32768 + j*8192.

    // ---- prologue: B(0), A(0), B(1), A-Q0/Q2(1); drain first 8 -> vmcnt(6) ----
#pragma unroll
    for (int j = 0; j < 4; j++) SQ(65536 + j * 8192, Bg + j * QG);
#pragma unroll
    for (int j = 0; j < 4; j++) SQ(j * 8192,         Ag + j * QG);
#pragma unroll
    for (int j = 0; j < 4; j++) SQ(98304 + j * 8192, Bg + j * QG + 128);
    SQ(32768,         Ag + 0 * QG + 128);
    SQ(32768 + 16384, Ag + 2 * QG + 128);
    SB(); asm volatile("s_waitcnt vmcnt(6)" ::: "memory"); SB();
    BAR();

    f32x4 acc[8][4];
    f32x4 zv = {0.f, 0.f, 0.f, 0.f};
#pragma unroll
    for (int i = 0; i < 8; i++)
#pragma unroll
        for (int j = 0; j < 4; j++) acc[i][j] = zv;

    int aoff_l = wr * 16384 + lread;                                    // bytes
    int boff_l = 65536 + (wc >> 1) * 16384 + (wc & 1) * 8192 + lread;   // bytes

    for (int t = 0; t < NTI; ++t) {
        int ab  = (t & 1) << 15;            // this tile's buffer offset
        int nab = ab ^ 32768;
        int abl = ab + aoff_l;
        int bbl = ab + boff_l;
        bf16x8 alo[4][2], ahi[4][2], bv[4][2];

        // ======== SP0: read A-lo + B-all ; stage A-Q1/Q3(t+1) ; 32 MFMA ========
#pragma unroll
        for (int mi = 0; mi < 4; mi++) {
            alo[mi][0] = *(const bf16x8*)&shm[(abl + mi * 2048) >> 4];
            alo[mi][1] = *(const bf16x8*)&shm[(abl + mi * 2048 + 1024) >> 4];
        }
#pragma unroll
        for (int ni = 0; ni < 2; ni++) {
            bv[ni][0]     = *(const bf16x8*)&shm[(bbl + ni * 2048) >> 4];
            bv[ni][1]     = *(const bf16x8*)&shm[(bbl + ni * 2048 + 1024) >> 4];
            bv[ni + 2][0] = *(const bf16x8*)&shm[(bbl + 4096 + ni * 2048) >> 4];
            bv[ni + 2][1] = *(const bf16x8*)&shm[(bbl + 4096 + ni * 2048 + 1024) >> 4];
        }
        if (t + 1 < NTI) {
            SQ(nab + 8192,  Ag + 1 * QG + (size_t)(t + 1) * 128);
            SQ(nab + 24576, Ag + 3 * QG + (size_t)(t + 1) * 128);
        }
        BAR();
        __builtin_amdgcn_s_setprio(1);
#pragma unroll
        for (int mi = 0; mi < 4; mi++)
#pragma unroll
            for (int ni = 0; ni < 4; ni++) {
                acc[mi][ni] = __builtin_amdgcn_mfma_f32_16x16x32_bf16(alo[mi][0], bv[ni][0], acc[mi][ni], 0, 0, 0);
                acc[mi][ni] = __builtin_amdgcn_mfma_f32_16x16x32_bf16(alo[mi][1], bv[ni][1], acc[mi][ni], 0, 0, 0);
            }
        __builtin_amdgcn_s_setprio(0);
        if (t < NTI - 1) { SB(); asm volatile("s_waitcnt vmcnt(8)" ::: "memory"); SB(); }
        else             { SB(); asm volatile("s_waitcnt vmcnt(0)" ::: "memory"); SB(); }
        BAR();

        // ======== SP1: read A-hi ; stage B(t+2)+A-Q0/Q2(t+2) ; 32 MFMA ========
#pragma unroll
        for (int mi = 0; mi < 4; mi++) {
            ahi[mi][0] = *(const bf16x8*)&shm[(abl + 8192 + mi * 2048) >> 4];
            ahi[mi][1] = *(const bf16x8*)&shm[(abl + 8192 + mi * 2048 + 1024) >> 4];
        }
        if (t + 2 < NTI) {
#pragma unroll
            for (int j = 0; j < 4; j++)
                SQ(ab + 65536 + j * 8192, Bg + j * QG + (size_t)(t + 2) * 128);
            SQ(ab,         Ag + 0 * QG + (size_t)(t + 2) * 128);
            SQ(ab + 16384, Ag + 2 * QG + (size_t)(t + 2) * 128);
        }
        BAR();
        __builtin_amdgcn_s_setprio(1);
#pragma unroll
        for (int mi = 0; mi < 4; mi++)
#pragma unroll
            for (int ni = 0; ni < 4; ni++) {
                acc[mi + 4][ni] = __builtin_amdgcn_mfma_f32_16x16x32_bf16(ahi[mi][0], bv[ni][0], acc[mi + 4][ni], 0, 0, 0);
                acc[mi + 4][ni] = __builtin_amdgcn_mfma_f32_16x16x32_bf16(ahi[mi][1], bv[ni][1], acc[mi + 4][ni], 0, 0, 0);
            }
        __builtin_amdgcn_s_setprio(0);
        if      (t + 2 < NTI)  { SB(); asm volatile("s_waitcnt vmcnt(8)" ::: "memory"); SB(); }
        else if (t == NTI - 2) { SB(); asm volatile("s_waitcnt vmcnt(2)" ::: "memory"); SB(); }
        else                   { SB(); asm volatile("s_waitcnt vmcnt(0)" ::: "memory"); SB(); }
        BAR();
    }

    // ---- epilogue ----
    int rbase = wr * 128 + (lane >> 4) * 4;
    int cbase = wc * 64 + (lane & 15);

    if (EPI == 0) {
        size_t rowg = (size_t)e * C_ + (size_t)mt * 256;
        float bb4[4];
#pragma unroll
        for (int ni = 0; ni < 4; ni++)
            bb4[ni] = bias[(size_t)e * N + nt * 256 + cbase + ni * 16];
#pragma unroll
        for (int mi = 0; mi < 8; mi++) {
#pragma unroll
            for (int rr2 = 0; rr2 < 4; rr2++) {
                int m = rbase + mi * 16 + rr2;
                size_t rb = (rowg + (size_t)m) * (size_t)N + nt * 256 + cbase;
#pragma unroll
                for (int ni = 0; ni < 4; ni++) {
                    float v = acc[mi][ni][rr2] + bb4[ni];
                    float u2 = 1.5957691216057308f * (v + 0.044715f * v * v * v);
                    float gl = v * __frcp_rn(1.f + __expf(-u2));
                    hout[rb + ni * 16] = f2bf(gl);
                }
            }
        }
    } else {
        float bb4[4];
#pragma unroll
        for (int ni = 0; ni < 4; ni++)
            bb4[ni] = bias[(size_t)e * N + nt * 256 + cbase + ni * 16];
#pragma unroll
        for (int mi = 0; mi < 8; mi++) {
#pragma unroll
            for (int rr2 = 0; rr2 < 4; rr2++) {
                int c = mt * 256 + rbase + mi * 16 + rr2;
                int tok = token_slot[e * C_ + c];
                if (tok < 0) continue;
                float g = gate_slot[e * C_ + c];
                size_t rb = (size_t)tok * (size_t)N + nt * 256 + cbase;
#pragma unroll
                for (int ni = 0; ni < 4; ni++) {
                    float v = (acc[mi][ni][rr2] + bb4[ni]) * g;
                    fout[rb + ni * 16] = v;
                }
            }
        }
    }
}

extern "C" void kernel_launch(void* const* d_in, const int* in_sizes, int n_in,
                              void* d_out, int out_size, void* d_ws, size_t ws_size,
                              hipStream_t stream)
{
    const float* x   = (const float*)d_in[0];
    const float* wgp = (const float*)d_in[1];
    const float* w1  = (const float*)d_in[2];
    const float* b1  = (const float*)d_in[3];
    const float* w2  = (const float*)d_in[4];
    const float* b2  = (const float*)d_in[5];
    float* out = (float*)d_out;

    char* ws = (char*)d_ws;
    unsigned short* w1t  = (unsigned short*)(ws);                    // 268435456 B
    unsigned short* w2t  = (unsigned short*)(ws + 268435456ull);     // 268435456 B
    unsigned short* disp = (unsigned short*)(ws + 536870912ull);     //  33554432 B
    unsigned short* hbuf = (unsigned short*)(ws + 570425344ull);     // 134217728 B
    int*   expert_id  = (int*)  (ws + 704643072ull);
    float* gate_tok   = (float*)(ws + 704675840ull);
    float* gates_all  = (float*)(ws + 704708608ull);
    int*   token_slot = (int*)  (ws + 704970752ull);
    float* gate_slot  = (float*)(ws + 705003520ull);

    zero_kernel<<<4096, 256, 0, stream>>>(out, out_size);
    transpose_cvt<<<8 * 32 * 128, 256, 0, stream>>>(w1, w1t, 2048, 8192);
    transpose_cvt<<<8 * 128 * 32, 256, 0, stream>>>(w2, w2t, 8192, 2048);
    gating_kernel<<<2048, 256, 0, stream>>>(x, wgp, expert_id, gate_tok, gates_all);
    scan_kernel<<<1, 1024, 0, stream>>>(expert_id, gate_tok, gates_all, token_slot, gate_slot, out + OUTN);
    gather_kernel<<<8192, 256, 0, stream>>>(x, token_slot, disp);
    gemm2sp<0, 2048, 8192><<<1024, 512, 0, stream>>>(disp, w1t, b1, hbuf, nullptr, nullptr, nullptr, 4, 32);
    gemm2sp<1, 8192, 2048><<<256, 512, 0, stream>>>(hbuf, w2t, b2, nullptr, out, token_slot, gate_slot, 4, 8);
}

// Round 5
// 893.576 us; speedup vs baseline: 1.0333x; 1.0333x over previous
//
#include <hip/hip_runtime.h>
#include <stdint.h>

#define E_ 8
#define S_ 8192
#define H_ 2048
#define F_ 8192
#define C_ 1024
#define OUTN (S_*H_)

typedef __bf16 bf16x8 __attribute__((ext_vector_type(8)));
typedef float  f32x4  __attribute__((ext_vector_type(4)));
typedef unsigned short us8 __attribute__((ext_vector_type(8)));

__device__ __forceinline__ unsigned short f2bf(float f) {
    union { float f; unsigned u; } v; v.f = f;
    unsigned r = (v.u + 0x7FFFu + ((v.u >> 16) & 1u)) >> 16;
    return (unsigned short)r;
}

__device__ __forceinline__ void gload16(const void* g, void* l) {
    auto gp = (const __attribute__((address_space(1))) void*)(unsigned long long)(uintptr_t)g;
    auto lp = (__attribute__((address_space(3))) void*)(unsigned int)(uintptr_t)l;
    __builtin_amdgcn_global_load_lds(gp, lp, 16, 0, 0);
}

#define SB() __builtin_amdgcn_sched_barrier(0)
#define BAR() do { SB(); __builtin_amdgcn_s_barrier(); SB(); } while(0)
// inline-asm ds_read_b128 with literal offset; counted lgkm waits (rule #18: SB after)
#define DSR(d, a, o) asm volatile("ds_read_b128 %0, %1 offset:" #o : "=v"(d) : "v"(a))
#define WLGKM(n) do { asm volatile("s_waitcnt lgkmcnt(" #n ")" ::: "memory"); SB(); } while(0)
#define WVM(n)   do { asm volatile("s_waitcnt vmcnt(" #n ")"   ::: "memory"); SB(); } while(0)
#define MM(accv, af, bf) accv = __builtin_amdgcn_mfma_f32_16x16x32_bf16(af, bf, accv, 0, 0, 0)

// ---------------- zero d_out ----------------
__global__ void zero_kernel(float* __restrict__ o, int n) {
    int i = blockIdx.x * blockDim.x + threadIdx.x;
    int st = gridDim.x * blockDim.x;
    for (; i < n; i += st) o[i] = 0.f;
}

// ---------------- transpose + fp32->bf16: dst[e][n][k] = src[e][k][n] ----------------
__global__ __launch_bounds__(256)
void transpose_cvt(const float* __restrict__ src, unsigned short* __restrict__ dst,
                   int R, int Cc)
{
    __shared__ float t[64][65];
    int tilesR = R >> 6, tilesC = Cc >> 6;
    int per_e = tilesR * tilesC;
    int bid = blockIdx.x;
    int e  = bid / per_e;
    int rm = bid - e * per_e;
    int tc = rm / tilesR;
    int tr = rm - tc * tilesR;

    const float* s = src + (size_t)e * R * Cc + (size_t)(tr * 64) * Cc + tc * 64;
    int tid = threadIdx.x;
    int rr = tid >> 4;
    int cc = (tid & 15) << 2;
#pragma unroll
    for (int i = 0; i < 4; i++) {
        float4 v = *(const float4*)(s + (size_t)(rr + i * 16) * Cc + cc);
        t[rr + i * 16][cc + 0] = v.x;
        t[rr + i * 16][cc + 1] = v.y;
        t[rr + i * 16][cc + 2] = v.z;
        t[rr + i * 16][cc + 3] = v.w;
    }
    __syncthreads();
    int nl = tid >> 2;
    int kq = (tid & 3) << 4;
    us8 o0, o1;
#pragma unroll
    for (int i = 0; i < 8; i++) o0[i] = f2bf(t[kq + i][nl]);
#pragma unroll
    for (int i = 0; i < 8; i++) o1[i] = f2bf(t[kq + 8 + i][nl]);
    unsigned short* d = dst + (size_t)e * R * Cc + (size_t)(tc * 64 + nl) * R + tr * 64 + kq;
    *reinterpret_cast<us8*>(d)     = o0;
    *reinterpret_cast<us8*>(d + 8) = o1;
}

// ---------------- gating ----------------
__global__ __launch_bounds__(256)
void gating_kernel(const float* __restrict__ x, const float* __restrict__ wg,
                   int* __restrict__ expert_id, float* __restrict__ gate_tok,
                   float* __restrict__ gates_all)
{
    int lane = threadIdx.x & 63;
    int wid  = threadIdx.x >> 6;
    int s = blockIdx.x * 4 + wid;
    const float* xs = x + (size_t)s * H_;
    float p[8];
#pragma unroll
    for (int j = 0; j < 8; j++) p[j] = 0.f;
    for (int h = lane; h < H_; h += 64) {
        float xv = xs[h];
        const float4* w4 = (const float4*)(wg + (size_t)h * 8);
        float4 a = w4[0], b = w4[1];
        p[0] += xv * a.x; p[1] += xv * a.y; p[2] += xv * a.z; p[3] += xv * a.w;
        p[4] += xv * b.x; p[5] += xv * b.y; p[6] += xv * b.z; p[7] += xv * b.w;
    }
#pragma unroll
    for (int off = 32; off; off >>= 1) {
#pragma unroll
        for (int j = 0; j < 8; j++) p[j] += __shfl_xor(p[j], off);
    }
    if (lane == 0) {
        float mx = p[0];
#pragma unroll
        for (int j = 1; j < 8; j++) mx = fmaxf(mx, p[j]);
        float ex[8], sum = 0.f;
#pragma unroll
        for (int j = 0; j < 8; j++) { ex[j] = expf(p[j] - mx); sum += ex[j]; }
        float inv = 1.f / sum;
        int am = 0; float best = p[0];
#pragma unroll
        for (int j = 1; j < 8; j++) if (p[j] > best) { best = p[j]; am = j; }
        expert_id[s] = am;
        gate_tok[s]  = expf(best - mx) * inv;
        float* ga = gates_all + (size_t)s * 8;
#pragma unroll
        for (int j = 0; j < 8; j++) ga[j] = ex[j] * inv;
    }
}

// ---------------- single-block capacity scan + l_aux + exp_counts ----------------
__global__ __launch_bounds__(1024)
void scan_kernel(const int* __restrict__ expert_id,
                 const float* __restrict__ gate_tok,
                 const float* __restrict__ gates_all,
                 int* __restrict__ token_slot,
                 float* __restrict__ gate_slot,
                 float* __restrict__ out_tail)
{
    __shared__ unsigned long long wt0[16], wt1[16];
    __shared__ unsigned long long tot0s, tot1s;
    __shared__ float red[1024 * 8];

    int tid = threadIdx.x;
    for (int i = tid; i < E_ * C_; i += 1024) token_slot[i] = -1;

    int ids[8];
#pragma unroll
    for (int j = 0; j < 8; j++) ids[j] = expert_id[tid * 8 + j];

    unsigned long long c0 = 0, c1 = 0;
#pragma unroll
    for (int j = 0; j < 8; j++) {
        int e = ids[j];
        unsigned long long inc = 1ull << ((e & 3) * 16);
        if (e < 4) c0 += inc; else c1 += inc;
    }
    unsigned long long s0 = c0, s1 = c1;
    int lane = tid & 63, w = tid >> 6;
#pragma unroll
    for (int off = 1; off < 64; off <<= 1) {
        unsigned long long t0 = __shfl_up(s0, off);
        unsigned long long t1 = __shfl_up(s1, off);
        if (lane >= off) { s0 += t0; s1 += t1; }
    }
    if (lane == 63) { wt0[w] = s0; wt1[w] = s1; }
    __syncthreads();
    unsigned long long off0 = 0, off1 = 0;
    for (int i = 0; i < w; i++) { off0 += wt0[i]; off1 += wt1[i]; }
    unsigned long long p0 = off0 + s0 - c0;
    unsigned long long p1 = off1 + s1 - c1;

#pragma unroll
    for (int j = 0; j < 8; j++) {
        int stok = tid * 8 + j;
        int e = ids[j];
        int sh = (e & 3) * 16;
        int slot = (int)(((e < 4 ? p0 : p1) >> sh) & 0xFFFFull);
        if (slot < C_) {
            token_slot[e * C_ + slot] = stok;
            gate_slot[e * C_ + slot]  = gate_tok[stok];
        }
        if (e < 4) p0 += 1ull << sh; else p1 += 1ull << sh;
    }
    if (tid == 1023) { tot0s = off0 + s0; tot1s = off1 + s1; }

    float me[8];
#pragma unroll
    for (int e2 = 0; e2 < 8; e2++) me[e2] = 0.f;
#pragma unroll
    for (int j = 0; j < 8; j++) {
        const float* ga = gates_all + (size_t)(tid * 8 + j) * 8;
#pragma unroll
        for (int e2 = 0; e2 < 8; e2++) me[e2] += ga[e2];
    }
#pragma unroll
    for (int e2 = 0; e2 < 8; e2++) red[tid * 8 + e2] = me[e2];
    __syncthreads();
    for (int st = 512; st > 0; st >>= 1) {
        if (tid < st) {
#pragma unroll
            for (int e2 = 0; e2 < 8; e2++) red[tid * 8 + e2] += red[(tid + st) * 8 + e2];
        }
        __syncthreads();
    }
    if (tid == 0) {
        float laux = 0.f;
#pragma unroll
        for (int e2 = 0; e2 < 8; e2++) {
            unsigned long long tv = (e2 < 4) ? tot0s : tot1s;
            float cnt = (float)((tv >> ((e2 & 3) * 16)) & 0xFFFFull);
            laux += red[e2] * cnt;
            out_tail[1 + e2] = cnt;
        }
        out_tail[0] = laux * (8.f / (8192.f * 8192.f));
    }
}

// ---------------- gather dispatched rows (fp32 -> bf16) ----------------
__global__ __launch_bounds__(256)
void gather_kernel(const float* __restrict__ x, const int* __restrict__ token_slot,
                   unsigned short* __restrict__ disp)
{
    int slot = blockIdx.x;
    int tok = token_slot[slot];
    int t = threadIdx.x;
    us8* d = reinterpret_cast<us8*>(disp + (size_t)slot * H_ + t * 8);
    if (tok < 0) {
        us8 z;
#pragma unroll
        for (int i = 0; i < 8; i++) z[i] = 0;
        *d = z;
        return;
    }
    const float4* s4 = (const float4*)(x + (size_t)tok * H_ + t * 8);
    float4 a = s4[0], b = s4[1];
    us8 o;
    o[0] = f2bf(a.x); o[1] = f2bf(a.y); o[2] = f2bf(a.z); o[3] = f2bf(a.w);
    o[4] = f2bf(b.x); o[5] = f2bf(b.y); o[6] = f2bf(b.z); o[7] = f2bf(b.w);
    *d = o;
}

// ====== 256x256 bf16 GEMM, read-ahead counted-lgkm schedule (T2+T3+T4+T5) ======
// A [E*1024][K] bf16, B [E][N][K] bf16 (pre-transposed). BM=BN=256, BK=64,
// 512 thr = 8 waves (2M x 4N). LDS 128 KiB dbuf. st_16x32 swizzle (T2).
// Per K-tile t (2 barriers only):
//  P0: asm-read bhi(t)[4];  lgkmcnt(4); MFMA (lo,lo)   <- alo/blo drain done, bhi in flight
//  P1: asm-read ahi(t)[8];  lgkmcnt(8); MFMA (lo,hi)   <- bhi done, ahi in flight
//  P2:                      lgkmcnt(0); MFMA (hi,lo); BAR
//  P3: stage A,B(t+2)->buf(t) [8]; vmcnt(8|0); BAR; asm-read alo,blo(t+1)[12]; MFMA (hi,hi)
// vmcnt(8) is a REAL wait: drains tile(t-1)'s 8 staging loads = buf(t+1) ready.
template<int EPI, int K, int N>
__global__ __launch_bounds__(512, 2)
void gemmra(const unsigned short* __restrict__ A,
            const unsigned short* __restrict__ B,
            const float* __restrict__ bias,
            unsigned short* __restrict__ hout,
            float* __restrict__ fout,
            const int* __restrict__ token_slot,
            const float* __restrict__ gate_slot,
            int Mt, int Nt)
{
    __shared__ char lds[131072];
    constexpr int KB  = K * 2;                 // global row pitch (bytes)
    constexpr int QG  = 64 * KB;               // 64-row quarter pitch (bytes)
    constexpr int NTI = K / 64;                // K-tiles (>=4 here)

    int nwg = gridDim.x;
    int bid = blockIdx.x;
    int cpx = nwg >> 3;
    int wg  = (bid & 7) * cpx + (bid >> 3);    // XCD-contiguous
    int per_e = Mt * Nt;
    int e  = wg / per_e;
    int r  = wg - e * per_e;
    int nt = r / Mt;
    int mt = r - nt * Mt;

    int tid  = threadIdx.x;
    int lane = tid & 63;
    int wid  = tid >> 6;
    int wr = wid >> 2, wc = wid & 3;

    const char* Ag = (const char*)(A + ((size_t)e * 1024 + (size_t)mt * 256) * (size_t)K);
    const char* Bg = (const char*)(B + ((size_t)e * N    + (size_t)nt * 256) * (size_t)K);

    // staging source offset (inverse st_16x32 swizzle on global src)
    int r16s   = (tid >> 2) & 15;
    int scs    = ((tid & 3) * 16) ^ ((r16s & 8) << 2);
    int colblk = (tid >> 6) & 1;
    int rb0    = tid >> 7;
    int off0 = (rb0 * 16 + r16s) * KB + colblk * 64 + scs;
    int widb = wid * 1024;

    // swizzled LDS read offset (bytes within an 8KB quarter)
    int lread = (lane & 15) * 64 + (((lane >> 4) * 16) ^ ((lane & 8) << 2));

    auto SQ = [&](int dstbyte, const char* src) {
        gload16(src + off0, (char*)lds + dstbyte + widb);
    };
    // LDS map: Abuf(b) = b*32768 + q*8192 (q=0..3); Bbuf(b) = 65536 + b*32768 + q*8192.

    // ---- prologue staging: A(0),B(0)->buf0 ; A(1),B(1)->buf1 ----
#pragma unroll
    for (int j = 0; j < 4; j++) SQ(j * 8192,          Ag + j * QG);
#pragma unroll
    for (int j = 0; j < 4; j++) SQ(65536 + j * 8192,  Bg + j * QG);
#pragma unroll
    for (int j = 0; j < 4; j++) SQ(32768 + j * 8192,  Ag + j * QG + 128);
#pragma unroll
    for (int j = 0; j < 4; j++) SQ(98304 + j * 8192,  Bg + j * QG + 128);
    WVM(8);
    BAR();

    unsigned a0 = (unsigned)(uintptr_t)lds + wr * 16384 + lread;
    unsigned b0 = (unsigned)(uintptr_t)lds + 65536 + (wc >> 1) * 16384 + (wc & 1) * 8192 + lread;

    bf16x8 alo[4][2], ahi[4][2], blo[2][2], bhi[2][2];

    // prologue reads: alo(0), blo(0) from buf0
    DSR(alo[0][0], a0, 0);    DSR(alo[0][1], a0, 1024);
    DSR(alo[1][0], a0, 2048); DSR(alo[1][1], a0, 3072);
    DSR(alo[2][0], a0, 4096); DSR(alo[2][1], a0, 5120);
    DSR(alo[3][0], a0, 6144); DSR(alo[3][1], a0, 7168);
    DSR(blo[0][0], b0, 0);    DSR(blo[0][1], b0, 1024);
    DSR(blo[1][0], b0, 2048); DSR(blo[1][1], b0, 3072);

    f32x4 acc[8][4];
    f32x4 zv = {0.f, 0.f, 0.f, 0.f};
#pragma unroll
    for (int i = 0; i < 8; i++)
#pragma unroll
        for (int j = 0; j < 4; j++) acc[i][j] = zv;

    for (int t = 0; t < NTI; ++t) {
        int bsel = (t & 1) << 15;
        unsigned av  = a0 + bsel;
        unsigned bv  = b0 + bsel;
        unsigned avn = av ^ 32768;
        unsigned bvn = bv ^ 32768;

        // ---- P0: read bhi(t); lgkm(4); MFMA (lo,lo) ----
        DSR(bhi[0][0], bv, 4096); DSR(bhi[0][1], bv, 5120);
        DSR(bhi[1][0], bv, 6144); DSR(bhi[1][1], bv, 7168);
        WLGKM(4);
        __builtin_amdgcn_s_setprio(1);
#pragma unroll
        for (int mi = 0; mi < 4; mi++)
#pragma unroll
            for (int ni = 0; ni < 2; ni++) {
                MM(acc[mi][ni], alo[mi][0], blo[ni][0]);
                MM(acc[mi][ni], alo[mi][1], blo[ni][1]);
            }
        __builtin_amdgcn_s_setprio(0);

        // ---- P1: read ahi(t); lgkm(8); MFMA (lo,hi) ----
        DSR(ahi[0][0], av, 8192);  DSR(ahi[0][1], av, 9216);
        DSR(ahi[1][0], av, 10240); DSR(ahi[1][1], av, 11264);
        DSR(ahi[2][0], av, 12288); DSR(ahi[2][1], av, 13312);
        DSR(ahi[3][0], av, 14336); DSR(ahi[3][1], av, 15360);
        WLGKM(8);
        __builtin_amdgcn_s_setprio(1);
#pragma unroll
        for (int mi = 0; mi < 4; mi++)
#pragma unroll
            for (int ni = 0; ni < 2; ni++) {
                MM(acc[mi][ni + 2], alo[mi][0], bhi[ni][0]);
                MM(acc[mi][ni + 2], alo[mi][1], bhi[ni][1]);
            }
        __builtin_amdgcn_s_setprio(0);

        // ---- P2: lgkm(0); MFMA (hi,lo); BAR ----
        WLGKM(0);
        __builtin_amdgcn_s_setprio(1);
#pragma unroll
        for (int mi = 0; mi < 4; mi++)
#pragma unroll
            for (int ni = 0; ni < 2; ni++) {
                MM(acc[mi + 4][ni], ahi[mi][0], blo[ni][0]);
                MM(acc[mi + 4][ni], ahi[mi][1], blo[ni][1]);
            }
        __builtin_amdgcn_s_setprio(0);
        BAR();

        // ---- P3: stage t+2 -> buf(t); vmcnt; BAR; read alo,blo(t+1); MFMA (hi,hi) ----
        if (t + 2 < NTI) {
            size_t ko = (size_t)(t + 2) * 128;
#pragma unroll
            for (int j = 0; j < 4; j++) SQ(bsel + j * 8192,         Ag + j * QG + ko);
#pragma unroll
            for (int j = 0; j < 4; j++) SQ(bsel + 65536 + j * 8192, Bg + j * QG + ko);
            WVM(8);
        } else {
            WVM(0);
        }
        BAR();
        if (t + 1 < NTI) {
            DSR(alo[0][0], avn, 0);    DSR(alo[0][1], avn, 1024);
            DSR(alo[1][0], avn, 2048); DSR(alo[1][1], avn, 3072);
            DSR(alo[2][0], avn, 4096); DSR(alo[2][1], avn, 5120);
            DSR(alo[3][0], avn, 6144); DSR(alo[3][1], avn, 7168);
            DSR(blo[0][0], bvn, 0);    DSR(blo[0][1], bvn, 1024);
            DSR(blo[1][0], bvn, 2048); DSR(blo[1][1], bvn, 3072);
        }
        __builtin_amdgcn_s_setprio(1);
#pragma unroll
        for (int mi = 0; mi < 4; mi++)
#pragma unroll
            for (int ni = 0; ni < 2; ni++) {
                MM(acc[mi + 4][ni + 2], ahi[mi][0], bhi[ni][0]);
                MM(acc[mi + 4][ni + 2], ahi[mi][1], bhi[ni][1]);
            }
        __builtin_amdgcn_s_setprio(0);
    }

    // ---- epilogue ----
    int rbase = wr * 128 + (lane >> 4) * 4;
    int cbase = wc * 64 + (lane & 15);

    if (EPI == 0) {
        size_t rowg = (size_t)e * C_ + (size_t)mt * 256;
        float bb4[4];
#pragma unroll
        for (int ni = 0; ni < 4; ni++)
            bb4[ni] = bias[(size_t)e * N + nt * 256 + cbase + ni * 16];
#pragma unroll
        for (int mi = 0; mi < 8; mi++) {
#pragma unroll
            for (int rr2 = 0; rr2 < 4; rr2++) {
                int m = rbase + mi * 16 + rr2;
                size_t rb = (rowg + (size_t)m) * (size_t)N + nt * 256 + cbase;
#pragma unroll
                for (int ni = 0; ni < 4; ni++) {
                    float v = acc[mi][ni][rr2] + bb4[ni];
                    float u2 = 1.5957691216057308f * (v + 0.044715f * v * v * v);
                    float gl = v * __frcp_rn(1.f + __expf(-u2));
                    hout[rb + ni * 16] = f2bf(gl);
                }
            }
        }
    } else {
        float bb4[4];
#pragma unroll
        for (int ni = 0; ni < 4; ni++)
            bb4[ni] = bias[(size_t)e * N + nt * 256 + cbase + ni * 16];
#pragma unroll
        for (int mi = 0; mi < 8; mi++) {
#pragma unroll
            for (int rr2 = 0; rr2 < 4; rr2++) {
                int c = mt * 256 + rbase + mi * 16 + rr2;
                int tok = token_slot[e * C_ + c];
                if (tok < 0) continue;
                float g = gate_slot[e * C_ + c];
                size_t rb = (size_t)tok * (size_t)N + nt * 256 + cbase;
#pragma unroll
                for (int ni = 0; ni < 4; ni++) {
                    float v = (acc[mi][ni][rr2] + bb4[ni]) * g;
                    fout[rb + ni * 16] = v;
                }
            }
        }
    }
}

extern "C" void kernel_launch(void* const* d_in, const int* in_sizes, int n_in,
                              void* d_out, int out_size, void* d_ws, size_t ws_size,
                              hipStream_t stream)
{
    const float* x   = (const float*)d_in[0];
    const float* wgp = (const float*)d_in[1];
    const float* w1  = (const float*)d_in[2];
    const float* b1  = (const float*)d_in[3];
    const float* w2  = (const float*)d_in[4];
    const float* b2  = (const float*)d_in[5];
    float* out = (float*)d_out;

    char* ws = (char*)d_ws;
    unsigned short* w1t  = (unsigned short*)(ws);                    // 268435456 B
    unsigned short* w2t  = (unsigned short*)(ws + 268435456ull);     // 268435456 B
    unsigned short* disp = (unsigned short*)(ws + 536870912ull);     //  33554432 B
    unsigned short* hbuf = (unsigned short*)(ws + 570425344ull);     // 134217728 B
    int*   expert_id  = (int*)  (ws + 704643072ull);
    float* gate_tok   = (float*)(ws + 704675840ull);
    float* gates_all  = (float*)(ws + 704708608ull);
    int*   token_slot = (int*)  (ws + 704970752ull);
    float* gate_slot  = (float*)(ws + 705003520ull);

    zero_kernel<<<4096, 256, 0, stream>>>(out, out_size);
    transpose_cvt<<<8 * 32 * 128, 256, 0, stream>>>(w1, w1t, 2048, 8192);
    transpose_cvt<<<8 * 128 * 32, 256, 0, stream>>>(w2, w2t, 8192, 2048);
    gating_kernel<<<2048, 256, 0, stream>>>(x, wgp, expert_id, gate_tok, gates_all);
    scan_kernel<<<1, 1024, 0, stream>>>(expert_id, gate_tok, gates_all, token_slot, gate_slot, out + OUTN);
    gather_kernel<<<8192, 256, 0, stream>>>(x, token_slot, disp);
    gemmra<0, 2048, 8192><<<1024, 512, 0, stream>>>(disp, w1t, b1, hbuf, nullptr, nullptr, nullptr, 4, 32);
    gemmra<1, 8192, 2048><<<256, 512, 0, stream>>>(hbuf, w2t, b2, nullptr, out, token_slot, gate_slot, 4, 8);
}